// Round 8
// baseline (388.710 us; speedup 1.0000x reference)
//
#include <hip/hip_runtime.h>
#include <hip/hip_cooperative_groups.h>
#include <stdint.h>

namespace cg = cooperative_groups;

#define NB 8
#define NPRED 25200
#define NTOP 1000
#define NCLS 80
#define CONF_T 0.25f
#define IOU_THR 0.45f
#define MAXWH 4096.0f
#define CAP 2048
#define NBINS 1025
#define SBPB 197      // ceil(25200/128)
#define NBLK 256      // 1 block per CU -> cooperative co-residency guaranteed
#define NTHR 256

typedef unsigned long long u64;

// ---------------------------------------------------------------------------
// One cooperative kernel, 5 phases separated by grid.sync():
//  1 score+hist   (all 256 blocks, grid-stride over 1576 tiles of 128 preds)
//  2 B + compact  (all blocks; per-block B recompute in LDS)
//  3 sort         (blocks 0-7: bitonic 2048 in LDS, gather top-1000)
//  4 iou          (all 256 blocks = 8 batches x 32 row-groups, transposed mask)
//  5 scan + out   (blocks 0-7; batched named forward loads + skip-chain)
// ---------------------------------------------------------------------------
__global__ __launch_bounds__(256, 1) void k_all(
    const float* __restrict__ x,
    float* __restrict__ msc, int* __restrict__ cls,
    unsigned* hist, unsigned* cnt, u64* cand,          // overlay region: no restrict
    float* __restrict__ det, float* __restrict__ offb,
    int* __restrict__ nvv, u64* maskT,
    float* __restrict__ out)
{
#pragma clang fp contract(off)
    cg::grid_group grid = cg::this_grid();
    __shared__ __align__(16) float smf[10880];   // 43520 B phase-shared buffer
    __shared__ int sBv[NB];
    __shared__ u64 kbs[16];

    const int t = threadIdx.x;
    const int wave = t >> 6, lane = t & 63;
    const int blk0 = blockIdx.x;

    //=== Phase 1: score/class/histogram ====================================
    {
        const float4* x4 = (const float4*)x;
        const long long TOT4 = (long long)NB * NPRED * 85 / 4;
        for (int tile = blk0; tile < NB * SBPB; tile += NBLK) {
            int b = tile / SBPB, blk = tile % SBPB;
            long long base4 = ((long long)b * NPRED + (long long)blk * 128) * 85 / 4;
            for (int k = 0; k < 11; ++k) {           // 11*256 >= 2720 float4
                int ib = k * 256 + wave * 64;        // wave-uniform LDS base
                int fi = ib + lane;
                if (fi < 2720) {
                    long long gi = base4 + fi;
                    if (gi >= TOT4) gi = TOT4 - 1;   // tail clamp, outputs guarded
                    __builtin_amdgcn_global_load_lds(
                        (const __attribute__((address_space(1))) void*)(x4 + gi),
                        (__attribute__((address_space(3))) void*)(smf + (size_t)ib * 4),
                        16, 0, 0);
                }
            }
            __syncthreads();
            if (t < 128) {
                int pred = blk * 128 + t;
                if (pred < NPRED) {
                    const float* p = &smf[t * 85];
                    float obj = p[4];
                    float best = p[5];
                    int bid = 0;
                    for (int c = 1; c < NCLS; ++c) {
                        float v = p[5 + c];
                        if (v > best) { best = v; bid = c; }  // strict >: first occ.
                    }
                    float score = obj * best;
                    int q = b * NPRED + pred;
                    msc[q] = (score > CONF_T) ? score : -1.0f;
                    cls[q] = bid;
                    if (score > CONF_T) {
                        int bin = (int)(__float_as_uint(score) >> 14) - 0xFA00;
                        bin = bin < 0 ? 0 : (bin > 1024 ? 1024 : bin);
                        atomicAdd(&hist[b * NBINS + bin], 1u);
                    }
                }
            }
            __syncthreads();
        }
    }
    grid.sync();

    //=== Phase 2: boundary bins (per-block) + compact ======================
    {
        for (int rep = 0; rep < 2; ++rep) {          // waves 0-3 x 2 = 8 batches
            int bb = wave + rep * 4;
            const unsigned* h = hist + bb * NBINS;
            int hi2 = 1024 - 16 * lane;
            unsigned sum = 0;
            for (int k = 0; k < 16; ++k) sum += h[hi2 - k];
            if (lane == 63) sum += h[0];
            unsigned v = sum;
            for (int d = 1; d < 64; d <<= 1) {
                unsigned o = __shfl_up(v, d);
                if (lane >= d) v += o;
            }
            unsigned excl = v - sum;
            u64 ball = __ballot(v >= NTOP);
            int B = 0;
            if (ball != 0) {
                int sel = __builtin_ctzll(ball);
                if (lane == sel) {
                    unsigned run = excl;
                    for (int k = 0; k < 16; ++k) {
                        run += h[hi2 - k];
                        if (run >= NTOP) { B = hi2 - k; break; }
                    }
                }
                B = __shfl(B, sel);
            }
            if (lane == 0) sBv[bb] = B;
        }
        __syncthreads();
        for (int i = blk0 * NTHR + t; i < NB * NPRED; i += NBLK * NTHR) {
            int b = i / NPRED;
            float s = msc[i];
            if (s > CONF_T) {
                unsigned bits = __float_as_uint(s);
                int bin = (int)(bits >> 14) - 0xFA00;
                bin = bin < 0 ? 0 : (bin > 1024 ? 1024 : bin);
                if (bin >= sBv[b]) {
                    unsigned slot = atomicAdd(&cnt[b], 1u);
                    if (slot < CAP) {
                        int p = i - b * NPRED;
                        cand[(size_t)b * CAP + slot] = ((u64)(~bits) << 32) | (unsigned)p;
                    }
                }
            }
        }
    }
    grid.sync();

    //=== Phase 3: bitonic sort + gather (blocks 0-7) =======================
    if (blk0 < NB) {
        u64* keys = (u64*)smf;                       // 16384 B
        const int b = blk0;
        unsigned c = cnt[b]; if (c > CAP) c = CAP;
        if (t == 0) nvv[b] = (int)(c < NTOP ? c : NTOP);
        for (int i = t; i < CAP; i += NTHR)
            keys[i] = (i < (int)c) ? cand[(size_t)b * CAP + i] : ~0ULL;
        __syncthreads();
        for (unsigned k = 2; k <= CAP; k <<= 1) {
            for (unsigned j = k >> 1; j > 0; j >>= 1) {
                for (unsigned tt = (unsigned)t; tt < CAP / 2; tt += NTHR) {
                    unsigned i = ((tt & ~(j - 1)) << 1) | (tt & (j - 1));
                    unsigned pi = i | j;
                    bool up = ((i & k) == 0);
                    u64 a = keys[i], d = keys[pi];
                    bool sw = up ? (a > d) : (a < d);
                    if (sw) { keys[i] = d; keys[pi] = a; }
                }
                __syncthreads();
            }
        }
        for (int r = t; r < NTOP; r += NTHR) {
            u64 key = keys[r];
            unsigned p = (unsigned)key;
            float score = __uint_as_float(~(unsigned)(key >> 32));
            bool v = score > CONF_T;
            float o0 = 0, o1 = 0, o2 = 0, o3 = 0, o4 = 0, o5 = 0;
            float f0 = 0, f1 = 0, f2 = 0, f3 = 0;
            if (v) {
                const float* xp = x + ((size_t)b * NPRED + p) * 85;
                float xc = xp[0], yc = xp[1], w = xp[2], h = xp[3];
                float hw = w * 0.5f, hh = h * 0.5f;
                o0 = xc - hw; o1 = yc - hh; o2 = xc + hw; o3 = yc + hh;
                o4 = score;
                float cf = (float)cls[(size_t)b * NPRED + p];
                o5 = cf;
                float co = cf * MAXWH;
                f0 = o0 + co; f1 = o1 + co; f2 = o2 + co; f3 = o3 + co;
            }
            size_t d6 = ((size_t)b * NTOP + r) * 6;
            det[d6 + 0] = o0; det[d6 + 1] = o1; det[d6 + 2] = o2;
            det[d6 + 3] = o3; det[d6 + 4] = o4; det[d6 + 5] = o5;
            size_t d4 = ((size_t)b * NTOP + r) * 4;
            offb[d4 + 0] = f0; offb[d4 + 1] = f1; offb[d4 + 2] = f2; offb[d4 + 3] = f3;
        }
    }
    grid.sync();

    //=== Phase 4: IoU bitmask, transposed (all 256 blocks) =================
    {
        float4* bx4 = (float4*)smf;                  // 16000 B
        float* area = smf + 4000;                    //  4000 B
        const int b = blk0 >> 5;
        const int rg = blk0 & 31;
        const float4* ob = (const float4*)(offb + (size_t)b * NTOP * 4);
        for (int i = t; i < NTOP; i += NTHR) {
            float4 v = ob[i];
            bx4[i] = v;
            area[i] = (v.z - v.x) * (v.w - v.y);
        }
        __syncthreads();
        const int i = rg * 32 + (t & 31);
        const int q = t >> 5;
        if (i < NTOP) {
            float4 A = bx4[i];
            float areaA = area[i];
            u64* mt = maskT + (size_t)b * 16 * NTOP;
            for (int wi = 0; wi < 2; ++wi) {
                int w = q * 2 + wi;
                u64 bits = 0;
                int c0 = w * 64;
                for (int cc = 0; cc < 64; ++cc) {
                    int col = c0 + cc;
                    if (col >= NTOP) break;
                    float4 Bb = bx4[col];
                    float ltx = fmaxf(A.x, Bb.x), lty = fmaxf(A.y, Bb.y);
                    float rbx = fminf(A.z, Bb.z), rby = fminf(A.w, Bb.w);
                    float ww = fmaxf(rbx - ltx, 0.0f), hh = fmaxf(rby - lty, 0.0f);
                    float inter = ww * hh;
                    float iou = inter / (((areaA + area[col]) - inter) + 1e-9f);
                    if (iou > IOU_THR && col != i) bits |= (1ULL << cc);
                }
                mt[(size_t)w * NTOP + i] = bits;
            }
        }
    }
    grid.sync();

    //=== Phase 5: greedy scan + masked output (blocks 0-7) =================
    if (blk0 >= NB) return;
    {
        const int b = blk0;
        const u64* mt = maskT + (size_t)b * 16 * NTOP;
        const int nv = nvv[b];
        if (wave == 0) {
            unsigned hitbits = 0;
            u64 dcur = mt[lane];
#define FWLOAD(H) u64 f##H = 0; if (g + H < 16) { \
            int rh = (g + H) * 64 + lane; if (rh > NTOP - 1) rh = NTOP - 1; \
            f##H = mt[(size_t)g * NTOP + rh]; }
#define FWUSE(H) if (g + H < 16) hitbits |= ((f##H & kb) != 0ULL) ? (1u << (g + H)) : 0u;
#pragma unroll
            for (int g = 0; g < 16; ++g) {
                // issue ALL of this group's loads up front (batched, overlap chain)
                u64 dnxt = 0;
                if (g + 1 < 16) {
                    int rn = (g + 1) * 64 + lane;
                    if (rn > NTOP - 1) rn = NTOP - 1;
                    dnxt = mt[(size_t)(g + 1) * NTOP + rn];
                }
                FWLOAD(1)  FWLOAD(2)  FWLOAD(3)  FWLOAD(4)  FWLOAD(5)
                FWLOAD(6)  FWLOAD(7)  FWLOAD(8)  FWLOAD(9)  FWLOAD(10)
                FWLOAD(11) FWLOAD(12) FWLOAD(13) FWLOAD(14) FWLOAD(15)

                int rem = nv - g * 64;
                u64 vb = rem >= 64 ? ~0ULL : (rem <= 0 ? 0ULL : ((1ULL << rem) - 1ULL));
                u64 preS = __ballot(((hitbits >> g) & 1u) != 0u);
                u64 nzb = __ballot(dcur != 0ULL);    // only these rows can modify
                u64 avail = vb & ~preS;
                u64 kb = 0, low = 0;
                while (true) {                       // skip-chain: iterate modifiers
                    u64 w2 = nzb & avail & ~low;
                    if (w2 == 0ULL) { kb |= avail & ~low; break; }
                    int ttv = __builtin_ctzll(w2);
                    u64 upto = (ttv == 63) ? ~0ULL : ((1ULL << (ttv + 1)) - 1ULL);
                    kb |= avail & upto & ~low;       // bulk-keep the run up to ttv
                    unsigned lo2 = (unsigned)__builtin_amdgcn_readlane((int)(unsigned)dcur, ttv);
                    unsigned hi2 = (unsigned)__builtin_amdgcn_readlane((int)(unsigned)(dcur >> 32), ttv);
                    avail &= ~(((u64)hi2 << 32) | (u64)lo2);
                    low = upto;
                }
                if (lane == 0) kbs[g] = kb;

                FWUSE(1)  FWUSE(2)  FWUSE(3)  FWUSE(4)  FWUSE(5)
                FWUSE(6)  FWUSE(7)  FWUSE(8)  FWUSE(9)  FWUSE(10)
                FWUSE(11) FWUSE(12) FWUSE(13) FWUSE(14) FWUSE(15)
                dcur = dnxt;
            }
#undef FWLOAD
#undef FWUSE
        }
        __syncthreads();
        const float2* dp2 = (const float2*)(det + (size_t)b * NTOP * 6);
        float2* op2 = (float2*)(out + (size_t)b * NTOP * 6);
        for (int e = t; e < NTOP * 3; e += NTHR) {
            int r = e / 3;
            u64 kb = kbs[r >> 6];
            bool keep = (kb >> (r & 63)) & 1ULL;
            float2 v = dp2[e];
            float2 z;
            z.x = keep ? v.x : 0.0f;
            z.y = keep ? v.y : 0.0f;
            op2[e] = z;
        }
    }
}

// ---------------------------------------------------------------------------
extern "C" void kernel_launch(void* const* d_in, const int* in_sizes, int n_in,
                              void* d_out, int out_size, void* d_ws, size_t ws_size,
                              hipStream_t stream) {
    const float* x = (const float*)d_in[0];
    char* ws = (char*)d_ws;
    float* msc = (float*)(ws);                       //       0 .. 806400
    int* cls = (int*)(ws + 806400);                  //  806400 .. 1612800
    float* det = (float*)(ws + 1612800);             // 1612800 .. 1804800
    float* offb = (float*)(ws + 1804800);            // 1804800 .. 1932800
    int* nvv = (int*)(ws + 1932800);                 // 1932800 .. 1932832
    u64* maskT = (u64*)(ws + 1964800);               // 1964800 .. 2988800
    // overlays in mask region (consumed by phases 2/3 before phase 4 writes):
    unsigned* hist = (unsigned*)(ws + 1964800);      // 32800
    unsigned* cnt = (unsigned*)(ws + 1997600);       // 32
    u64* cand = (u64*)(ws + 1997664);                // 131072
    float* out = (float*)d_out;

    hipMemsetAsync(hist, 0, 32832, stream);          // hist + cnt
    void* args[] = {(void*)&x, (void*)&msc, (void*)&cls, (void*)&hist,
                    (void*)&cnt, (void*)&cand, (void*)&det, (void*)&offb,
                    (void*)&nvv, (void*)&maskT, (void*)&out};
    hipLaunchCooperativeKernel((const void*)k_all, dim3(NBLK), dim3(NTHR),
                               args, 0, stream);
}